// Round 8
// baseline (125.666 us; speedup 1.0000x reference)
//
#include <hip/hip_runtime.h>

typedef _Float16 half2_t __attribute__((ext_vector_type(2)));
typedef _Float16 half4_t __attribute__((ext_vector_type(4)));
typedef _Float16 half8_t __attribute__((ext_vector_type(8)));
typedef __fp16   fp16x2  __attribute__((ext_vector_type(2)));
typedef float    f32x4   __attribute__((ext_vector_type(4)));

#define BS 128
#define DH 64
#define NB 8   // balls per block; grid = 4096/NB = 512 = 2 blocks/CU exactly

__device__ __forceinline__ half2_t pkrtz(float x, float y) {
  fp16x2 t = __builtin_amdgcn_cvt_pkrtz(x, y);
  return __builtin_bit_cast(half2_t, t);
}

__device__ __forceinline__ half8_t cvt8(const float4 a, const float4 b) {
  half2_t h0 = pkrtz(a.x, a.y);
  half2_t h1 = pkrtz(a.z, a.w);
  half2_t h2 = pkrtz(b.x, b.y);
  half2_t h3 = pkrtz(b.z, b.w);
  half4_t lo = __builtin_shufflevector(h0, h1, 0, 1, 2, 3);
  half4_t hi = __builtin_shufflevector(h2, h3, 0, 1, 2, 3);
  return __builtin_shufflevector(lo, hi, 0, 1, 2, 3, 4, 5, 6, 7);
}

// VT swizzle: conflict-free for BOTH the transposed half2 write (d varies per
// lane via bits>=2) and the b128 PV read (d=t*16+c varies via bits 0..3).
__device__ __forceinline__ int svt(int d) { return (d & 7) ^ ((d >> 2) & 7); }

__global__ __launch_bounds__(256, 1) void ball_attn_kernel(
    const float* __restrict__ Q, const float* __restrict__ Kk,
    const float* __restrict__ V, float* __restrict__ O) {
  // 32KB (K f32) + 32KB (VT f16 dbuf) + 16KB (Pl) = 80KB -> 2 blocks/CU.
  __shared__ __align__(16) float    Kf[BS * DH];       // [key][d] f32, XOR-swizzled units
  __shared__ __align__(16) _Float16 VT2[2][DH * BS];   // [d][key] f16, svt-swizzled
  __shared__ __align__(16) _Float16 Pl[4 * 16 * BS];   // per-wave P half-tile

  const int tid  = threadIdx.x;
  const int w    = tid >> 6;
  const int lane = tid & 63;
  const int c    = lane & 15;
  const int g    = lane >> 4;
  const int d0   = (tid & 15) * 4;  // V-staging: d block
  const int kgrp = tid >> 4;        // V-staging: key group

  const size_t ball0 = (size_t)blockIdx.x * NB;

  // K -> LDS f32 via global_load_lds: linear LDS dest (wave-uniform base +
  // lane*16B), per-lane PRE-SWIZZLED global source (u = u' ^ (row&7)).
  auto issueK = [&](const float* Kb) {
#pragma unroll
    for (int t = 0; t < 8; ++t) {
      const int row = 32 * w + 4 * t + g;
      const int u   = (lane & 15) ^ (row & 7);
      __builtin_amdgcn_global_load_lds(
          (const __attribute__((address_space(1))) unsigned int*)(Kb + row * DH + u * 4),
          (__attribute__((address_space(3))) unsigned int*)&Kf[(32 * w + 4 * t) * DH],
          16, 0, 0);
    }
  };
  auto loadV = [&](const float* Vb, float4* vr) {
#pragma unroll
    for (int it = 0; it < 4; ++it) {
      const int keyA = 2 * kgrp + 32 * it;
      vr[2 * it]     = *(const float4*)(Vb + (size_t)keyA * DH + d0);
      vr[2 * it + 1] = *(const float4*)(Vb + (size_t)(keyA + 1) * DH + d0);
    }
  };
  auto writeVT = [&](_Float16* vt, const float4* vr) {
#pragma unroll
    for (int it = 0; it < 4; ++it) {
      const int keyA = 2 * kgrp + 32 * it;
      const float* ap = (const float*)&vr[2 * it];
      const float* bp = (const float*)&vr[2 * it + 1];
#pragma unroll
      for (int j = 0; j < 4; ++j) {
        const int d = d0 + j;
        *(half2_t*)&vt[d * BS + (keyA ^ (svt(d) << 3))] = pkrtz(ap[j], bp[j]);
      }
    }
  };
  auto loadQ = [&](const float* Qb, float4* qr) {
#pragma unroll
    for (int m = 0; m < 2; ++m)
#pragma unroll
      for (int ks = 0; ks < 2; ++ks) {
        const float* qp = Qb + (w * 32 + m * 16 + c) * DH + ks * 32 + g * 8;
        qr[(m * 2 + ks) * 2]     = *(const float4*)qp;
        qr[(m * 2 + ks) * 2 + 1] = *(const float4*)(qp + 4);
      }
  };

  half8_t aq[2][2];  // loop-carried: Q fragments of current ball
  auto cvtQ = [&](const float4* qr) {
#pragma unroll
    for (int m = 0; m < 2; ++m)
#pragma unroll
      for (int ks = 0; ks < 2; ++ks)
        aq[m][ks] = cvt8(qr[(m * 2 + ks) * 2], qr[(m * 2 + ks) * 2 + 1]);
  };

  // ---- prologue: stage ball 0 (one overlapped round trip) ----
  {
    const size_t b_off = ball0 * (size_t)(BS * DH);
    issueK(Kk + b_off);
    float4 vr[8], qr[8];
    loadV(V + b_off, vr);
    loadQ(Q + b_off, qr);
    cvtQ(qr);
    writeVT(VT2[0], vr);
    __syncthreads();  // drains K gloads + reg loads; VT[0], Kf visible
  }

  int cur = 0;
#pragma unroll 1
  for (int i = 0; i < NB; ++i) {
    _Float16* vtcur = VT2[cur];
    float* Ob = O + (ball0 + i) * (size_t)(BS * DH);

    // ---- B: QK^T from Kf (LDS f32 -> f16 frags) ----
    f32x4 acc[2][8];
#pragma unroll
    for (int m = 0; m < 2; ++m)
#pragma unroll
      for (int kt = 0; kt < 8; ++kt) acc[m][kt] = (f32x4){0.f, 0.f, 0.f, 0.f};
#pragma unroll
    for (int kt = 0; kt < 8; ++kt)
#pragma unroll
      for (int ks = 0; ks < 2; ++ks) {
        const int row = kt * 16 + c;
        const int sr  = row & 7;
        const int u0  = 8 * ks + 2 * g;
        const float4 a = *(const float4*)&Kf[row * DH + ((u0 ^ sr) * 4)];
        const float4 b = *(const float4*)&Kf[row * DH + (((u0 + 1) ^ sr) * 4)];
        const half8_t bk = cvt8(a, b);
        acc[0][kt] = __builtin_amdgcn_mfma_f32_16x16x32_f16(aq[0][ks], bk, acc[0][kt], 0, 0, 0);
        acc[1][kt] = __builtin_amdgcn_mfma_f32_16x16x32_f16(aq[1][ks], bk, acc[1][kt], 0, 0, 0);
      }
    __syncthreads();  // barrier_a: all waves done reading Kf

    const bool pf = (i + 1 < NB);
    const size_t nb_off = (ball0 + i + 1) * (size_t)(BS * DH);
    if (pf) issueK(Kk + nb_off);  // flies across softmax+PV+store

    float4 vraw[8], qraw[8];

    // ================= m = 0 half =================
    float inv0[4];
    {
      float mx[4], sm[4];
#pragma unroll
      for (int r = 0; r < 4; ++r) {
        mx[r] = acc[0][0][r];
#pragma unroll
        for (int kt = 1; kt < 8; ++kt) mx[r] = fmaxf(mx[r], acc[0][kt][r]);
      }
#pragma unroll
      for (int r = 0; r < 4; ++r) {
        mx[r] = fmaxf(mx[r], __shfl_xor(mx[r], 1));
        mx[r] = fmaxf(mx[r], __shfl_xor(mx[r], 2));
        mx[r] = fmaxf(mx[r], __shfl_xor(mx[r], 4));
        mx[r] = fmaxf(mx[r], __shfl_xor(mx[r], 8));
        sm[r] = 0.f;
      }
#pragma unroll
      for (int kt = 0; kt < 8; ++kt)
#pragma unroll
        for (int r = 0; r < 4; ++r) {
          const float p = __expf((acc[0][kt][r] - mx[r]) * 0.125f);
          acc[0][kt][r] = p;
          sm[r] += p;
        }
#pragma unroll
      for (int r = 0; r < 4; ++r) {
        sm[r] += __shfl_xor(sm[r], 1);
        sm[r] += __shfl_xor(sm[r], 2);
        sm[r] += __shfl_xor(sm[r], 4);
        sm[r] += __shfl_xor(sm[r], 8);
        inv0[r] = __builtin_amdgcn_rcpf(sm[r]);
      }
#pragma unroll
      for (int kt = 0; kt < 8; ++kt)
#pragma unroll
        for (int r = 0; r < 4; ++r) {
          const int row = 4 * g + r;
          Pl[(w * 16 + row) * BS + ((kt * 16 + c) ^ ((row & 7) << 3))] =
              (_Float16)acc[0][kt][r];
        }
    }
    if (pf) loadV(V + nb_off, vraw);  // V_{i+1}: flies across PV m=0/m=1
    {
      f32x4 o[4];
#pragma unroll
      for (int t = 0; t < 4; ++t) o[t] = (f32x4){0.f, 0.f, 0.f, 0.f};
#pragma unroll
      for (int ks = 0; ks < 4; ++ks) {
        const int e0 = ks * 32 + g * 8;
        const half8_t pfg = *(const half8_t*)&Pl[(w * 16 + c) * BS + (e0 ^ ((c & 7) << 3))];
#pragma unroll
        for (int t = 0; t < 4; ++t) {
          const int rowd = t * 16 + c;
          const half8_t vf = *(const half8_t*)&vtcur[rowd * BS + (e0 ^ (svt(rowd) << 3))];
          o[t] = __builtin_amdgcn_mfma_f32_16x16x32_f16(pfg, vf, o[t], 0, 0, 0);
        }
      }
#pragma unroll
      for (int t = 0; t < 4; ++t)
#pragma unroll
        for (int r = 0; r < 4; ++r)
          Ob[(w * 32 + 4 * g + r) * DH + t * 16 + c] = o[t][r] * inv0[r];
    }

    // ================= m = 1 half =================
    float inv1[4];
    {
      float mx[4], sm[4];
#pragma unroll
      for (int r = 0; r < 4; ++r) {
        mx[r] = acc[1][0][r];
#pragma unroll
        for (int kt = 1; kt < 8; ++kt) mx[r] = fmaxf(mx[r], acc[1][kt][r]);
      }
#pragma unroll
      for (int r = 0; r < 4; ++r) {
        mx[r] = fmaxf(mx[r], __shfl_xor(mx[r], 1));
        mx[r] = fmaxf(mx[r], __shfl_xor(mx[r], 2));
        mx[r] = fmaxf(mx[r], __shfl_xor(mx[r], 4));
        mx[r] = fmaxf(mx[r], __shfl_xor(mx[r], 8));
        sm[r] = 0.f;
      }
#pragma unroll
      for (int kt = 0; kt < 8; ++kt)
#pragma unroll
        for (int r = 0; r < 4; ++r) {
          const float p = __expf((acc[1][kt][r] - mx[r]) * 0.125f);
          acc[1][kt][r] = p;
          sm[r] += p;
        }
#pragma unroll
      for (int r = 0; r < 4; ++r) {
        sm[r] += __shfl_xor(sm[r], 1);
        sm[r] += __shfl_xor(sm[r], 2);
        sm[r] += __shfl_xor(sm[r], 4);
        sm[r] += __shfl_xor(sm[r], 8);
        inv1[r] = __builtin_amdgcn_rcpf(sm[r]);
      }
      // Pl reuse: same wave already finished its m=0 PV reads (LDS ordered)
#pragma unroll
      for (int kt = 0; kt < 8; ++kt)
#pragma unroll
        for (int r = 0; r < 4; ++r) {
          const int row = 4 * g + r;
          Pl[(w * 16 + row) * BS + ((kt * 16 + c) ^ ((row & 7) << 3))] =
              (_Float16)acc[1][kt][r];
        }
    }
    if (pf) loadQ(Q + nb_off, qraw);  // Q_{i+1}: flies across PV m=1
    {
      f32x4 o[4];
#pragma unroll
      for (int t = 0; t < 4; ++t) o[t] = (f32x4){0.f, 0.f, 0.f, 0.f};
#pragma unroll
      for (int ks = 0; ks < 4; ++ks) {
        const int e0 = ks * 32 + g * 8;
        const half8_t pfg = *(const half8_t*)&Pl[(w * 16 + c) * BS + (e0 ^ ((c & 7) << 3))];
#pragma unroll
        for (int t = 0; t < 4; ++t) {
          const int rowd = t * 16 + c;
          const half8_t vf = *(const half8_t*)&vtcur[rowd * BS + (e0 ^ (svt(rowd) << 3))];
          o[t] = __builtin_amdgcn_mfma_f32_16x16x32_f16(pfg, vf, o[t], 0, 0, 0);
        }
      }
#pragma unroll
      for (int t = 0; t < 4; ++t)
#pragma unroll
        for (int r = 0; r < 4; ++r)
          Ob[(w * 32 + 16 + 4 * g + r) * DH + t * 16 + c] = o[t][r] * inv1[r];
    }

    if (pf) {
      cvtQ(qraw);
      writeVT(VT2[cur ^ 1], vraw);  // other buffer: no race with PV readers
    }
    __syncthreads();  // barrier_b: drains K gloads; VT[nxt] visible
    cur ^= 1;
  }
}

extern "C" void kernel_launch(void* const* d_in, const int* in_sizes, int n_in,
                              void* d_out, int out_size, void* d_ws, size_t ws_size,
                              hipStream_t stream) {
  const float* q = (const float*)d_in[0];
  const float* k = (const float*)d_in[1];
  const float* v = (const float*)d_in[2];
  float* out = (float*)d_out;
  const int nballs = in_sizes[0] / (BS * DH);  // 4096
  ball_attn_kernel<<<dim3(nballs / NB), dim3(256), 0, stream>>>(q, k, v, out);
}